// Round 6
// baseline (404.282 us; speedup 1.0000x reference)
//
#include <hip/hip_runtime.h>

// LightGCN forward on MI355X — slab-bucketed CSR build + dim-quartered,
// XCD-partitioned gather on a transposed bf16 table.
// Inputs: d_in[0] = edge_index int32 [2, E]; d_in[1] = emb_weight f32 [N, 64].
// Output: d_out = [emb0 (N*64) | out (N*64)] f32, out = mean(emb0..emb3).
// Assumes N <= 131072 (<=256 buckets). Here N=120000, E=2M, dst ~uniform.
//
// R1: LDS-scatter variant = 727 µs/layer (LDS-atomic serialization) — reverted.
// R2: paired-node dwordx2 gather: 53.3 -> 47.6 µs/gather (VALUBusy 57->41%).
// R4: 2-stage pipeline: ~null (47.0 µs) — NOT in-flight-depth-bound. FETCH=137MB
//     ≈ 8 XCDs re-fetching the 15.4MB table (4MB L2/XCD) at ~2.9 TB/s fabric.
// R5 (this round): transpose table to T[q][node][16 dims] (32 B quarter-rows);
//     block (b&3)=quarter, (b>>2) = 32-node group. With round-robin b%8->XCD,
//     each XCD owns a DISJOINT (quarter x node-parity) slice ~1.92 MB -> L2-
//     resident; table fabric traffic 120MB -> 15.4MB/layer. Wave = 8 nodes x
//     2 edge-subgroups x 4 lanes (dwordx2/lane); unpredicated clamped loads.

#define DIM 64
#define BN 512          // nodes per bucket
#define BSH 9
#define CHUNK 4096      // edges per scatter workgroup (2 WGs/CU overlap)

typedef unsigned short u16;
typedef unsigned int u32;

static __device__ __forceinline__ float bf2f_lo(u32 p) { return __uint_as_float(p << 16); }
static __device__ __forceinline__ float bf2f_hi(u32 p) { return __uint_as_float(p & 0xffff0000u); }
static __device__ __forceinline__ u16 f2bf(float f) {   // round-to-nearest-even
    unsigned u = __float_as_uint(f);
    return (u16)((u + 0x7fffu + ((u >> 16) & 1u)) >> 16);
}
static __device__ __forceinline__ u32 pack2(float a, float b) {
    return (u32)f2bf(a) | ((u32)f2bf(b) << 16);
}

__global__ void zero_cur(int* __restrict__ cursor) { cursor[threadIdx.x] = 0; }

// Per-chunk LDS counting-sort by bucket; slab space reserved with one global
// atomicAdd per (chunk,bucket). Unchanged (verified R1/R4).
__global__ void __launch_bounds__(512) c1_scatter(
        const int* __restrict__ src, const int* __restrict__ dst,
        int* __restrict__ cursor, u32* __restrict__ slab, int E, int CAP) {
    __shared__ u32 buf[CHUNK];
    __shared__ unsigned char bb[CHUNK];
    __shared__ int posb[256], startb[256], gbase[256];
    int w = blockIdx.x, tid = threadIdx.x;
    int lo = w * CHUNK, hi = min(lo + CHUNK, E);
    if (tid < 256) posb[tid] = 0;
    __syncthreads();
    for (int i = lo + tid; i < hi; i += 512) atomicAdd(&posb[dst[i] >> BSH], 1);
    __syncthreads();
    int x = 0;
    if (tid < 256) {
        x = posb[tid];
        gbase[tid] = x ? atomicAdd(cursor + tid, x) : 0;   // slab reservation
    }
    __syncthreads();
    for (int off = 1; off < 256; off <<= 1) {              // in-place scan of posb
        int t = (tid >= off && tid < 256) ? posb[tid - off] : 0;
        __syncthreads();
        if (tid < 256) posb[tid] += t;
        __syncthreads();
    }
    if (tid < 256) startb[tid] = posb[tid] - x;
    __syncthreads();
    if (tid < 256) posb[tid] = startb[tid];                // placement cursor
    __syncthreads();
    for (int i = lo + tid; i < hi; i += 512) {
        int d = dst[i], b = d >> BSH;
        int q = atomicAdd(&posb[b], 1);
        buf[q] = ((u32)src[i] << BSH) | (u32)(d & (BN - 1));
        bb[q] = (unsigned char)b;
    }
    __syncthreads();
    int n = hi - lo;
    for (int q = tid; q < n; q += 512) {                   // coalesced bucket-run writes
        int b = bb[q];
        slab[(size_t)b * CAP + gbase[b] + (q - startb[b])] = buf[q];
    }
}

// One WG per bucket: bucket_lo scan -> node-hist -> scan -> dis/row_se -> col.
__global__ void __launch_bounds__(512) c3_build(
        const u32* __restrict__ slab, const int* __restrict__ cursor,
        int* __restrict__ col, int2* __restrict__ row_se, float* __restrict__ dis,
        int N, int CAP, int NB) {
    __shared__ int cur[BN];
    __shared__ int ps[512];
    int b = blockIdx.x, tid = threadIdx.x;
    // exclusive prefix of bucket counts -> this bucket's lo (first 256 threads)
    int xc = (tid < NB) ? cursor[tid] : 0;
    if (tid < 256) ps[tid] = xc;
    __syncthreads();
    for (int off = 1; off < 256; off <<= 1) {
        int t = (tid >= off && tid < 256) ? ps[tid - off] : 0;
        __syncthreads();
        if (tid < 256) ps[tid] += t;
        __syncthreads();
    }
    int lo  = b ? ps[b - 1] : 0;
    int cnt = cursor[b];
    __syncthreads();

    int nodeBase = b << BSH;
    int nLoc = min(BN, N - nodeBase);
    const u32* sp = slab + (size_t)b * CAP;
    cur[tid] = 0;                                          // 512 nodes, 512 threads
    __syncthreads();
    for (int i = tid; i < cnt; i += 512) atomicAdd(&cur[sp[i] & (BN - 1)], 1);
    __syncthreads();
    int c0 = cur[tid];
    ps[tid] = c0;
    __syncthreads();
    for (int off = 1; off < 512; off <<= 1) {              // scan of node counts
        int t = (tid >= off) ? ps[tid - off] : 0;
        __syncthreads();
        ps[tid] += t;
        __syncthreads();
    }
    int base = ps[tid] - c0;                               // exclusive
    cur[tid] = base;                                       // placement cursor
    if (tid < nLoc) {
        dis[nodeBase + tid] = c0 ? rsqrtf((float)c0) : 0.f;
        row_se[nodeBase + tid] = make_int2(lo + base, lo + base + c0);
    }
    __syncthreads();
    for (int i = tid; i < cnt; i += 512) {
        u32 v = sp[i];
        int q = atomicAdd(&cur[v & (BN - 1)], 1);
        col[lo + q] = (int)(v >> BSH);       // confined to this WG's region
    }
}

// e0bT = transposed bf16(dis * emb0): T[q][node][16 dims] (8 u32 per entry).
// Also emits the exact f32 emb0 output.
__global__ void cvt_copy(const float4* __restrict__ emb, const float* __restrict__ dis,
                         u32* __restrict__ e0bT, float4* __restrict__ emb0_out,
                         int n4, int N) {
    int i = blockIdx.x * blockDim.x + threadIdx.x;
    if (i < n4) {
        float4 v = emb[i];
        int node = i >> 4;
        int q    = (i >> 2) & 3;
        int d4   = i & 3;
        float w = dis[node];
        uint2 o;
        o.x = pack2(w * v.x, w * v.y);
        o.y = pack2(w * v.z, w * v.w);
        *(uint2*)(e0bT + ((size_t)q * N + node) * 8 + 2 * d4) = o;
        emb0_out[i] = v;
    }
}

// Quartered gather body. Block: q = b&3, 32 nodes; wave = 8 nodes; per node,
// 8 lanes = 2 edge-subgroups (g) x 4 lanes (d4: dwordx2 = dims 16q+4*d4..+3).
// Per-lane round countdown m; loads UNPREDICATED (col clamped to E-1 — every
// col value is a valid node, so row loads are always in-bounds), invalid rows
// zeroed via cndmask. Col prefetched 2 rounds ahead, row 1 ahead.
#define GATHERQ_BODY(CURTAB)                                                   \
    float s0 = 0.f, s1 = 0.f, s2 = 0.f, s3 = 0.f;                              \
    {                                                                          \
        const u32* tq = (CURTAB) + ((size_t)q * N) * 8 + 2 * d4;               \
        int Em1 = E - 1;                                                       \
        int m = (end - start - g + 1) >> 1;                                    \
        int e = start + g;                                                     \
        u32 cA = col[min(e, Em1)];                                             \
        u32 cB = col[min(e + 2, Em1)];                                         \
        uint2 p = *(const uint2*)(tq + ((size_t)cA << 3));                     \
        if (m <= 0) { p.x = 0; p.y = 0; }                                      \
        int mm = m, ee = e + 4;                                                \
        while (__any(mm > 0)) {                                                \
            u32 cC = col[min(ee, Em1)];                                        \
            uint2 pn = *(const uint2*)(tq + ((size_t)cB << 3));                \
            if (mm <= 1) { pn.x = 0; pn.y = 0; }                               \
            s0 += bf2f_lo(p.x); s1 += bf2f_hi(p.x);                            \
            s2 += bf2f_lo(p.y); s3 += bf2f_hi(p.y);                            \
            p = pn; cB = cC; --mm; ee += 2;                                    \
        }                                                                      \
    }                                                                          \
    s0 += __shfl_xor(s0, 4); s1 += __shfl_xor(s1, 4);                          \
    s2 += __shfl_xor(s2, 4); s3 += __shfl_xor(s3, 4);

// Mid layer: nextT[q][node] = bf16(w^2 * sum of prescaled neighbor quarter-rows).
__global__ void __launch_bounds__(256) gatherq_mid(
        const int2* __restrict__ row_se, const int* __restrict__ col,
        const float* __restrict__ dis, const u32* __restrict__ cur,
        u32* __restrict__ next, int N, int E) {
    int b = blockIdx.x, tid = threadIdx.x;
    int q    = b & 3;
    int node = (b >> 2) * 32 + (tid >> 3);
    int g    = (tid >> 2) & 1;
    int d4   = tid & 3;
    bool vn  = node < N;
    int2 se  = vn ? row_se[node] : make_int2(0, 0);
    int start = se.x, end = se.y;
    GATHERQ_BODY(cur)
    if (vn && g == 0) {
        float w = dis[node], ww = w * w;
        uint2 o;
        o.x = pack2(ww * s0, ww * s1);
        o.y = pack2(ww * s2, ww * s3);
        *(uint2*)(next + ((size_t)q * N + node) * 8 + 2 * d4) = o;
    }
}

// Final layer fused with the mean epilogue:
// out = 0.25 * (e0 + (e1b + e2b)/w + e3),  e3 = w * sum(prescaled e2b rows).
__global__ void __launch_bounds__(256) gatherq_final(
        const int2* __restrict__ row_se, const int* __restrict__ col,
        const float* __restrict__ dis, const u32* __restrict__ cur /* e2bT */,
        const u32* __restrict__ e1b /* e1bT */, const float* __restrict__ emb0,
        float* __restrict__ out, int N, int E) {
    int b = blockIdx.x, tid = threadIdx.x;
    int q    = b & 3;
    int node = (b >> 2) * 32 + (tid >> 3);
    int g    = (tid >> 2) & 1;
    int d4   = tid & 3;
    bool vn  = node < N;
    int2 se  = vn ? row_se[node] : make_int2(0, 0);
    int start = se.x, end = se.y;
    GATHERQ_BODY(cur)
    if (vn && g == 0) {
        float w = dis[node];
        float inv = (w > 0.f) ? 1.0f / w : 0.f;
        size_t ti = ((size_t)q * N + node) * 8 + 2 * d4;
        uint2 q1 = *(const uint2*)(e1b + ti);
        uint2 q2 = *(const uint2*)(cur + ti);
        size_t fo = (size_t)node * 64 + q * 16 + d4 * 4;
        float4 e0 = *(const float4*)(emb0 + fo);
        float4 r;
        r.x = 0.25f * (e0.x + (bf2f_lo(q1.x) + bf2f_lo(q2.x)) * inv + w * s0);
        r.y = 0.25f * (e0.y + (bf2f_hi(q1.x) + bf2f_hi(q2.x)) * inv + w * s1);
        r.z = 0.25f * (e0.z + (bf2f_lo(q1.y) + bf2f_lo(q2.y)) * inv + w * s2);
        r.w = 0.25f * (e0.w + (bf2f_hi(q1.y) + bf2f_hi(q2.y)) * inv + w * s3);
        *(float4*)(out + fo) = r;
    }
}

extern "C" void kernel_launch(void* const* d_in, const int* in_sizes, int n_in,
                              void* d_out, int out_size, void* d_ws, size_t ws_size,
                              hipStream_t stream) {
    const int*   edge  = (const int*)d_in[0];
    const float* emb_w = (const float*)d_in[1];
    const int E = in_sizes[0] / 2;
    const int N = in_sizes[1] / DIM;
    const int* src = edge;         // edge_index[0]
    const int* dst = edge + E;     // edge_index[1]

    const int NB  = (N + BN - 1) >> BSH;          // <= 256
    const int nCh = (E + CHUNK - 1) / CHUNK;
    const int CAP = (E / (NB > 0 ? NB : 1)) * 2;  // 2x mean bucket load (uniform dst)

    float* out_base = (float*)d_out;
    float* emb0_out = out_base;                       // first half of d_out
    float* acc      = out_base + (size_t)N * DIM;     // second half -> out

    // ws: [dis: N][row_se: N int2][cursor: 256][col: E]
    //     [zone: slab (NB*CAP u32) overlaid later by e0bT|e1bT (2 * N*32 u32)]
    float* dis       = (float*)d_ws;
    int2*  row_se    = (int2*)(dis + ((N + 1) & ~1));
    int*   cursor    = (int*)(row_se + N);
    int*   col       = cursor + 256;
    u32*   slab      = (u32*)(col + E);
    u32*   e0bT      = slab;                          // overlays slab (dead after c3)
    u32*   e1bT      = e0bT + (size_t)N * 32;

    const int n4  = N * DIM / 4;
    const int BLK = 256;
    const int g4  = (n4 + BLK - 1) / BLK;
    const int NBK = (N + 31) / 32;                    // 32 nodes per block
    const int gQ  = 4 * NBK;                          // x4 dim-quarters

    // --- CSR build ---
    zero_cur<<<1, 256, 0, stream>>>(cursor);
    c1_scatter<<<nCh, 512, 0, stream>>>(src, dst, cursor, slab, E, CAP);
    c3_build<<<NB, 512, 0, stream>>>(slab, cursor, col, row_se, dis, N, CAP, NB);

    // Prescaled transposed bf16 table + exact emb0 output (slab dead now).
    cvt_copy<<<g4, BLK, 0, stream>>>((const float4*)emb_w, dis,
                                     e0bT, (float4*)emb0_out, n4, N);

    // Layer 1: e1bT = bf16(w*e1)
    gatherq_mid<<<gQ, BLK, 0, stream>>>(row_se, col, dis, e0bT, e1bT, N, E);
    // Layer 2: e2bT -> e0bT region (e0bT dead)
    gatherq_mid<<<gQ, BLK, 0, stream>>>(row_se, col, dis, e1bT, e0bT, N, E);
    // Layer 3 + mean epilogue
    gatherq_final<<<gQ, BLK, 0, stream>>>(row_se, col, dis, e0bT, e1bT,
                                          emb_w, acc, N, E);
}

// Round 9
// 262.013 us; speedup vs baseline: 1.5430x; 1.5430x over previous
//
#include <hip/hip_runtime.h>

// LightGCN forward on MI355X — slab-bucketed CSR build (parity-split padded col)
// + paired-node dwordx2 gather with uint4 col loads.
// Inputs: d_in[0] = edge_index int32 [2, E]; d_in[1] = emb_weight f32 [N, 64].
// Output: d_out = [emb0 (N*64) | out (N*64)] f32, out = mean(emb0..emb3).
// Assumes N <= 131072 (<=256 buckets). Here N=120000, E=2M, dst ~uniform.
//
// R1: LDS-scatter variant = 727 µs/layer (LDS-atomic serialization) — reverted.
// R2: paired-node dwordx2 gather: 53.3 -> 47.6 µs/gather.
// R4: 2-stage pipeline ~null — gather is L2-miss-fabric bound (~2.9 TB/s).
// R5: 32-B quartered table REGRESSED (FETCH 137->207 MB). Keep rows >= 128 B.
// R6: CRASHED — fusing cvt into c3_build raced the e0b-overlays-slab region.
//     Lesson: slab/e0b overlay is only legal with cvt as a SEPARATE kernel.
// R7: un-fused cvt; kept parity-split col + e1b parked in d_out second half.
// R8: container failed twice, no pytest traceback — same infra-flake signature
//     as R3 (R4 resubmit of identical source then passed). Source re-audited
//     (alignment, bounds, ws budget 29.3MB < proven 32.2MB, races): no defect.
//     Resubmitting identical R7 kernel.

#define DIM 64
#define BN 512          // nodes per bucket
#define BSH 9
#define CHUNK 4096      // edges per scatter workgroup (2 WGs/CU overlap)
#define PADB 4096       // per-bucket col padding (512 nodes * <=6 pad + align)

typedef unsigned short u16;
typedef unsigned int u32;

static __device__ __forceinline__ float bf2f_lo(u32 p) { return __uint_as_float(p << 16); }
static __device__ __forceinline__ float bf2f_hi(u32 p) { return __uint_as_float(p & 0xffff0000u); }
static __device__ __forceinline__ u16 f2bf(float f) {   // round-to-nearest-even
    unsigned u = __float_as_uint(f);
    return (u16)((u + 0x7fffu + ((u >> 16) & 1u)) >> 16);
}
static __device__ __forceinline__ u32 pack2(float a, float b) {
    return (u32)f2bf(a) | ((u32)f2bf(b) << 16);
}

__global__ void zero_cur(int* __restrict__ cursor) { cursor[threadIdx.x] = 0; }

// Per-chunk LDS counting-sort by bucket; slab space reserved with one global
// atomicAdd per (chunk,bucket). Unchanged (verified R1/R4).
__global__ void __launch_bounds__(512) c1_scatter(
        const int* __restrict__ src, const int* __restrict__ dst,
        int* __restrict__ cursor, u32* __restrict__ slab, int E, int CAP) {
    __shared__ u32 buf[CHUNK];
    __shared__ unsigned char bb[CHUNK];
    __shared__ int posb[256], startb[256], gbase[256];
    int w = blockIdx.x, tid = threadIdx.x;
    int lo = w * CHUNK, hi = min(lo + CHUNK, E);
    if (tid < 256) posb[tid] = 0;
    __syncthreads();
    for (int i = lo + tid; i < hi; i += 512) atomicAdd(&posb[dst[i] >> BSH], 1);
    __syncthreads();
    int x = 0;
    if (tid < 256) {
        x = posb[tid];
        gbase[tid] = x ? atomicAdd(cursor + tid, x) : 0;   // slab reservation
    }
    __syncthreads();
    for (int off = 1; off < 256; off <<= 1) {              // in-place scan of posb
        int t = (tid >= off && tid < 256) ? posb[tid - off] : 0;
        __syncthreads();
        if (tid < 256) posb[tid] += t;
        __syncthreads();
    }
    if (tid < 256) startb[tid] = posb[tid] - x;
    __syncthreads();
    if (tid < 256) posb[tid] = startb[tid];                // placement cursor
    __syncthreads();
    for (int i = lo + tid; i < hi; i += 512) {
        int d = dst[i], b = d >> BSH;
        int q = atomicAdd(&posb[b], 1);
        buf[q] = ((u32)src[i] << BSH) | (u32)(d & (BN - 1));
        bb[q] = (unsigned char)b;
    }
    __syncthreads();
    int n = hi - lo;
    for (int q = tid; q < n; q += 512) {                   // coalesced bucket-run writes
        int b = bb[q];
        slab[(size_t)b * CAP + gbase[b] + (q - startb[b])] = buf[q];
    }
}

// One WG per bucket: bucket_lo scan -> node-hist -> padded scan -> parity-split
// col placement. Per node: colA = even local positions (cA=(c+1)/2, padded to
// 4), then colB = odd positions (cB=c/2, padded to 4). sA 16-B aligned; pads
// zero-filled (col=0 is a valid row; tail adds are value-masked in the gather).
// NO table writes here — slab/e0b overlay requires slab dead first (R6 lesson).
__global__ void __launch_bounds__(512) c3_build(
        const u32* __restrict__ slab, const int* __restrict__ cursor,
        int* __restrict__ col, int2* __restrict__ row_se, float* __restrict__ dis,
        int N, int CAP, int NB) {
    __shared__ int cur[BN];      // hist, then placement counters
    __shared__ int sAv[BN];      // per-node colA start (global entries)
    __shared__ int pAv[BN];      // per-node padA
    __shared__ int ps[512];
    int b = blockIdx.x, tid = threadIdx.x;
    // exclusive prefix of raw bucket counts -> this bucket's raw lo
    int xc = (tid < NB) ? cursor[tid] : 0;
    if (tid < 256) ps[tid] = xc;
    __syncthreads();
    for (int off = 1; off < 256; off <<= 1) {
        int t = (tid >= off && tid < 256) ? ps[tid - off] : 0;
        __syncthreads();
        if (tid < 256) ps[tid] += t;
        __syncthreads();
    }
    int lo_raw = b ? ps[b - 1] : 0;
    int cnt = cursor[b];
    __syncthreads();
    int lo_pad = ((lo_raw + 3) & ~3) + b * PADB;           // 4-aligned bucket base

    int nodeBase = b << BSH;
    int nLoc = min(BN, N - nodeBase);
    const u32* sp = slab + (size_t)b * CAP;
    cur[tid] = 0;                                          // 512 nodes, 512 threads
    __syncthreads();
    for (int i = tid; i < cnt; i += 512) atomicAdd(&cur[sp[i] & (BN - 1)], 1);
    __syncthreads();
    int c0 = cur[tid];
    int cA = (c0 + 1) >> 1, cB = c0 >> 1;
    int padA = (cA + 3) & ~3;
    int padn = padA + ((cB + 3) & ~3);
    ps[tid] = padn;
    __syncthreads();
    for (int off = 1; off < 512; off <<= 1) {              // scan of padded sizes
        int t = (tid >= off) ? ps[tid - off] : 0;
        __syncthreads();
        ps[tid] += t;
        __syncthreads();
    }
    int sA = lo_pad + ps[tid] - padn;                      // exclusive -> colA start
    __syncthreads();
    cur[tid] = 0;                                          // placement counter
    sAv[tid] = sA; pAv[tid] = padA;
    if (tid < nLoc) {
        dis[nodeBase + tid] = c0 ? rsqrtf((float)c0) : 0.f;
        row_se[nodeBase + tid] = make_int2(sA, c0);        // (colA start, degree)
    }
    for (int p = cA; p < padA; ++p) col[sA + p] = 0;       // zero-fill pads
    int sB = sA + padA, padBn = padn - padA;
    for (int p = cB; p < padBn; ++p) col[sB + p] = 0;
    __syncthreads();
    for (int i = tid; i < cnt; i += 512) {                 // parity-split placement
        u32 v = sp[i];
        int ln = v & (BN - 1);
        int p = atomicAdd(&cur[ln], 1);
        int t = sAv[ln] + ((p & 1) ? pAv[ln] + (p >> 1) : (p >> 1));
        col[t] = (int)(v >> BSH);
    }
}

// e0b = bf16(dis * emb0) prescaled table; also emits the exact f32 emb0 output.
// SEPARATE kernel (after c3_build retires) — slab/e0b overlay is only then safe.
__global__ void cvt_copy(const float4* __restrict__ emb, const float* __restrict__ dis,
                         ushort4* __restrict__ e0b, float4* __restrict__ emb0_out, int n4) {
    int i = blockIdx.x * blockDim.x + threadIdx.x;
    if (i < n4) {
        float4 v = emb[i];
        float w = dis[i >> 4];
        ushort4 o;
        o.x = f2bf(w * v.x); o.y = f2bf(w * v.y);
        o.z = f2bf(w * v.z); o.w = f2bf(w * v.w);
        e0b[i] = o;
        emb0_out[i] = v;
    }
}

#define ACC4(P) { s0 += bf2f_lo((P).x); s1 += bf2f_hi((P).x);                  \
                  s2 += bf2f_lo((P).y); s3 += bf2f_hi((P).y); }
#define ROWLD(CI) (*(const uint2*)((CURTAB) + (((size_t)(u32)(CI)) << (SH)) + 2 * d))

// Paired-node gather body. Wave = 2 nodes (lane halves); subgroup g=(lane>>4)&1
// owns the node's parity-g edge list (contiguous, 16-B aligned, zero-padded);
// lane d=(lane&15) loads dwordx2 = dims 4d..4d+3 of the 128-B (or 256-B-strided)
// prescaled row. One round = 1 uint4 col load (broadcast across the 16 d-lanes)
// + 4 row loads. 2-stage rotation: issue round r's col+rows before accumulating
// round r-1. Tail: ONE value-masked round (pad cols are 0 -> valid row 0, adds
// suppressed by cndmask). Reduce across g via shfl_xor(16).
#define GATHERQ(CURTAB, SH)                                                    \
    float s0 = 0.f, s1 = 0.f, s2 = 0.f, s3 = 0.f;                              \
    {                                                                          \
        int cAq  = (c + 1) >> 1;                                               \
        int padA = (cAq + 3) & ~3;                                             \
        int mg   = g ? (c >> 1) : cAq;                                         \
        const int* cp = col + sA + (g ? padA : 0);                             \
        int nfull = mg >> 2;                                                   \
        uint2 p0, p1, p2, p3;                                                  \
        if (nfull > 0) {                                                       \
            uint4 cv = *(const uint4*)cp;                                      \
            p0 = ROWLD(cv.x); p1 = ROWLD(cv.y);                                \
            p2 = ROWLD(cv.z); p3 = ROWLD(cv.w);                                \
        }                                                                      \
        for (int r = 1; r < nfull; ++r) {                                      \
            uint4 cv = *(const uint4*)(cp + 4 * r);                            \
            uint2 q0 = ROWLD(cv.x), q1 = ROWLD(cv.y);                          \
            uint2 q2 = ROWLD(cv.z), q3 = ROWLD(cv.w);                          \
            ACC4(p0) ACC4(p1) ACC4(p2) ACC4(p3)                                \
            p0 = q0; p1 = q1; p2 = q2; p3 = q3;                                \
        }                                                                      \
        if (nfull > 0) { ACC4(p0) ACC4(p1) ACC4(p2) ACC4(p3) }                 \
        int t0 = nfull << 2;                                                   \
        if (t0 < mg) {                                                         \
            uint4 cv = *(const uint4*)(cp + t0);                               \
            uint2 pk;                                                          \
            pk = ROWLD(cv.x); if (t0 + 0 >= mg) { pk.x = 0; pk.y = 0; } ACC4(pk) \
            pk = ROWLD(cv.y); if (t0 + 1 >= mg) { pk.x = 0; pk.y = 0; } ACC4(pk) \
            pk = ROWLD(cv.z); if (t0 + 2 >= mg) { pk.x = 0; pk.y = 0; } ACC4(pk) \
            pk = ROWLD(cv.w); if (t0 + 3 >= mg) { pk.x = 0; pk.y = 0; } ACC4(pk) \
        }                                                                      \
    }                                                                          \
    s0 += __shfl_xor(s0, 16); s1 += __shfl_xor(s1, 16);                        \
    s2 += __shfl_xor(s2, 16); s3 += __shfl_xor(s3, 16);

// Mid layer: next[node] = bf16(w^2 * sum of prescaled neighbor rows).
// INSH/OUTSH = log2 row stride in u32 (5 = 128-B table, 6 = parked in 256-B out rows).
template<int INSH, int OUTSH>
__global__ void __launch_bounds__(256) gather_mid(
        const int2* __restrict__ row_se, const int* __restrict__ col,
        const float* __restrict__ dis, const u32* __restrict__ cur,
        u32* __restrict__ next, int N) {
    int t = blockIdx.x * blockDim.x + threadIdx.x;
    int pair = t >> 6, lane = t & 63;
    if (2 * pair >= N) return;
    int node = 2 * pair + (lane >> 5);
    int g = (lane >> 4) & 1, d = lane & 15;
    bool valid = node < N;
    int2 se = valid ? row_se[node] : make_int2(0, 0);
    int sA = se.x, c = se.y;
    const u32* CURTAB = cur; constexpr int SH = INSH;
    GATHERQ(CURTAB, SH)
    if (valid && g == 0) {
        float w = dis[node], ww = w * w;
        uint2 o;
        o.x = pack2(ww * s0, ww * s1);
        o.y = pack2(ww * s2, ww * s3);
        *(uint2*)(next + (((size_t)node) << OUTSH) + 2 * d) = o;
    }
}

// Final gather (layer 3) fused with the mean epilogue:
// out = 0.25 * (e0 + (e1b + e2b)/w + e3),  e3 = w * sum(prescaled e2b neighbors).
// e1b is parked in the first 128 B of each 256-B out row (stride 64 u32); each
// wave's q1 loads precede its dependent out stores in program order (same-wave
// load-before-store — the pattern verified in R1). e1b/out alias: no __restrict__.
__global__ void __launch_bounds__(256) gather_final(
        const int2* __restrict__ row_se, const int* __restrict__ col,
        const float* __restrict__ dis, const u32* __restrict__ cur /* e2b */,
        const u32* e1b, const float* __restrict__ emb0,
        float* out, int N) {
    int t = blockIdx.x * blockDim.x + threadIdx.x;
    int pair = t >> 6, lane = t & 63;
    if (2 * pair >= N) return;
    int node = 2 * pair + (lane >> 5);
    int g = (lane >> 4) & 1, d = lane & 15;
    bool valid = node < N;
    int2 se = valid ? row_se[node] : make_int2(0, 0);
    int sA = se.x, c = se.y;
    const u32* CURTAB = cur; constexpr int SH = 5;
    GATHERQ(CURTAB, SH)
    if (valid && g == 0) {
        float w = dis[node];
        float inv = (w > 0.f) ? 1.0f / w : 0.f;
        uint2 q1 = *(const uint2*)(e1b + ((size_t)node << 6) + 2 * d);
        uint2 q2 = *(const uint2*)(cur + ((size_t)node << 5) + 2 * d);
        size_t fo = (size_t)node * 64 + 4 * d;             // float units
        float4 e0 = *(const float4*)(emb0 + fo);
        float4 r;
        r.x = 0.25f * (e0.x + (bf2f_lo(q1.x) + bf2f_lo(q2.x)) * inv + w * s0);
        r.y = 0.25f * (e0.y + (bf2f_hi(q1.x) + bf2f_hi(q2.x)) * inv + w * s1);
        r.z = 0.25f * (e0.z + (bf2f_lo(q1.y) + bf2f_lo(q2.y)) * inv + w * s2);
        r.w = 0.25f * (e0.w + (bf2f_hi(q1.y) + bf2f_hi(q2.y)) * inv + w * s3);
        *(float4*)(out + fo) = r;
    }
}

extern "C" void kernel_launch(void* const* d_in, const int* in_sizes, int n_in,
                              void* d_out, int out_size, void* d_ws, size_t ws_size,
                              hipStream_t stream) {
    const int*   edge  = (const int*)d_in[0];
    const float* emb_w = (const float*)d_in[1];
    const int E = in_sizes[0] / 2;
    const int N = in_sizes[1] / DIM;
    const int* src = edge;         // edge_index[0]
    const int* dst = edge + E;     // edge_index[1]

    const int NB  = (N + BN - 1) >> BSH;          // <= 256
    const int nCh = (E + CHUNK - 1) / CHUNK;
    const int CAP = (E / (NB > 0 ? NB : 1)) * 2;  // 2x mean bucket load (uniform dst)

    float* out_base = (float*)d_out;
    float* emb0_out = out_base;                       // first half of d_out
    float* acc      = out_base + (size_t)N * DIM;     // second half -> out
    u32*   e1b      = (u32*)acc;                      // e1b row n = first 128 B of out row n

    // ws: [dis: N][row_se: N int2][cursor: 256][col: E + NB*PADB + 64]
    //     [zone: slab (NB*CAP u32) overlaid by e0b (N*32 u32) AFTER c3 retires]
    // total ~29.3 MB (< 32.2 MB the R1-verified layout used).
    float* dis       = (float*)d_ws;
    int2*  row_se    = (int2*)(dis + ((N + 1) & ~1));
    int*   cursor    = (int*)(row_se + N);
    int*   col       = cursor + 256;
    const int COLSZ  = E + NB * PADB + 64;            // multiple of 4 entries
    u32*   slab      = (u32*)(col + COLSZ);
    u32*   e0b       = slab;                          // overlays slab (dead after c3)

    const int BLK   = 256;
    const int n4    = N * DIM / 4;
    const int g4    = (n4 + BLK - 1) / BLK;
    const int PAIRS = (N + 1) / 2;                    // 2 nodes per 64-lane wave
    const int gW    = (PAIRS * 64 + BLK - 1) / BLK;

    // --- CSR build (parity-split padded col) ---
    zero_cur<<<1, 256, 0, stream>>>(cursor);
    c1_scatter<<<nCh, 512, 0, stream>>>(src, dst, cursor, slab, E, CAP);
    c3_build<<<NB, 512, 0, stream>>>(slab, cursor, col, row_se, dis, N, CAP, NB);

    // Prescaled bf16 table + exact emb0 output (slab dead now).
    cvt_copy<<<g4, BLK, 0, stream>>>((const float4*)emb_w, dis,
                                     (ushort4*)e0b, (float4*)emb0_out, n4);

    // Layer 1: e1b = bf16(w*e1), parked in out rows (stride 64 u32)
    gather_mid<5, 6><<<gW, BLK, 0, stream>>>(row_se, col, dis, e0b, e1b, N);
    // Layer 2: e2b -> e0b region (e0b dead), reading parked e1b (stride 64)
    gather_mid<6, 5><<<gW, BLK, 0, stream>>>(row_se, col, dis, e1b, e0b, N);
    // Layer 3 + mean epilogue (overwrites parked e1b rows with final out)
    gather_final<<<gW, BLK, 0, stream>>>(row_se, col, dis, e0b, e1b,
                                         emb_w, acc, N);
}